// Round 1
// baseline (523.554 us; speedup 1.0000x reference)
//
#include <hip/hip_runtime.h>

#define C_CLASSES 1000
#define N_SLOTS   128
#define D_DIM     512
#define B_SAMPLES 4096

// ---------------------------------------------------------------------------
// Kernel A: cls[p] = argmax_k batch_targets[mask[p], k]   (first-index on tie)
// One wave (64 lanes) per sample position p.
// ---------------------------------------------------------------------------
__global__ __launch_bounds__(256) void argmax_kernel(
    const float* __restrict__ targets,   // [B, C]
    const int*   __restrict__ mask,      // [B]
    int*         __restrict__ cls)       // [B]
{
    const int wave = threadIdx.x >> 6;
    const int lane = threadIdx.x & 63;
    const int p = blockIdx.x * 4 + wave;
    if (p >= B_SAMPLES) return;

    const int sample = mask[p];
    const float* row = targets + (long long)sample * C_CLASSES;

    float bestv = -INFINITY;
    int   besti = 0;
    for (int k = lane; k < C_CLASSES; k += 64) {
        float v = row[k];
        if (v > bestv) { bestv = v; besti = k; }   // strict > keeps first index
    }
    // 64-lane reduction, tie -> smaller index (global first occurrence)
    for (int off = 32; off > 0; off >>= 1) {
        float ov = __shfl_down(bestv, off, 64);
        int   oi = __shfl_down(besti, off, 64);
        if (ov > bestv || (ov == bestv && oi < besti)) { bestv = ov; besti = oi; }
    }
    if (lane == 0) cls[p] = besti;
}

// ---------------------------------------------------------------------------
// Kernel B: per-class sequential simulation on (confidence, source-index) only.
// One 64-lane block per class. src encoding: >=0 -> memory row j of this class,
// <0 -> batch_features row (-(src+1)).
// ---------------------------------------------------------------------------
__global__ __launch_bounds__(64) void simulate_kernel(
    const float* __restrict__ confidences,  // [C, N]
    const int*   __restrict__ bconf,        // [B]
    const int*   __restrict__ mask,         // [B]
    const int*   __restrict__ cls,          // [B]
    int*         __restrict__ src_out)      // [C, N]
{
    const int c    = blockIdx.x;
    const int lane = threadIdx.x;

    __shared__ float cf[N_SLOTS];
    __shared__ int   src[N_SLOTS];
    __shared__ float ncf[N_SLOTS];
    __shared__ int   nsrc[N_SLOTS];

    cf[lane]      = confidences[c * N_SLOTS + lane];
    cf[lane + 64] = confidences[c * N_SLOTS + lane + 64];
    src[lane]      = lane;
    src[lane + 64] = lane + 64;
    __syncthreads();

    for (int base = 0; base < B_SAMPLES; base += 64) {
        const int p     = base + lane;
        const int myc   = cls[p];
        const int mys   = mask[p];
        const int mycnf = bconf[mys];

        unsigned long long m = __ballot(myc == c);
        while (m) {
            const int b = __ffsll(m) - 1;     // lowest set bit -> smallest p first
            m &= m - 1;

            const float conf = (float)__shfl(mycnf, b, 64);
            const int   feat = __shfl(mys, b, 64);
            const float last = cf[N_SLOTS - 1];

            if (conf > last) {                 // uniform across the wave
                // Build shifted arrays: data from slot i+1, confidence from slot i
                // (reference: row shifted, confidences NOT shifted, last overwritten).
                ncf[lane]  = cf[lane];
                nsrc[lane] = src[lane + 1];
                if (lane + 64 < N_SLOTS - 1) {
                    ncf[lane + 64]  = cf[lane + 64];
                    nsrc[lane + 64] = src[lane + 65];
                } else {
                    ncf[N_SLOTS - 1]  = conf;
                    nsrc[N_SLOTS - 1] = -(feat + 1);
                }
                __syncthreads();

                // Stable descending rank (== jnp.argsort(-ncf) stable):
                // rank(i) = #{j : v_j > v_i} + #{j < i : v_j == v_i}
                const float v0 = ncf[lane], v1 = ncf[lane + 64];
                int r0 = 0, r1 = 0;
                for (int j = 0; j < N_SLOTS; ++j) {
                    const float vj = ncf[j];
                    r0 += (vj > v0) || (vj == v0 && j < lane);
                    r1 += (vj > v1) || (vj == v1 && j < lane + 64);
                }
                const int s0 = nsrc[lane], s1 = nsrc[lane + 64];
                __syncthreads();
                cf[r0] = v0;  src[r0] = s0;
                cf[r1] = v1;  src[r1] = s1;
                __syncthreads();
            }
        }
    }

    src_out[c * N_SLOTS + lane]      = src[lane];
    src_out[c * N_SLOTS + lane + 64] = src[lane + 64];
}

// ---------------------------------------------------------------------------
// Kernel C: permuted bulk copy. One wave per (class, slot) row of 512 floats.
// ---------------------------------------------------------------------------
__global__ __launch_bounds__(256) void writeback_kernel(
    const float* __restrict__ memory,   // [C, N, D]
    const float* __restrict__ feats,    // [B, D]
    const int*   __restrict__ src,      // [C, N]
    float*       __restrict__ out)      // [C, N, D]
{
    const int wave = threadIdx.x >> 6;
    const int lane = threadIdx.x & 63;
    const long long row = (long long)blockIdx.x * 4 + wave;   // 0 .. C*N-1
    const int c = (int)(row >> 7);                            // row / 128
    const int s = src[row];

    const float* sp;
    if (s >= 0) sp = memory + ((long long)c * N_SLOTS + s) * D_DIM;
    else        sp = feats + (long long)(-(s + 1)) * D_DIM;
    float* dp = out + row * D_DIM;

    const float4* sp4 = (const float4*)sp;
    float4* dp4 = (float4*)dp;
    float4 a = sp4[lane];
    float4 b = sp4[lane + 64];
    dp4[lane]      = a;
    dp4[lane + 64] = b;
}

// ---------------------------------------------------------------------------
extern "C" void kernel_launch(void* const* d_in, const int* in_sizes, int n_in,
                              void* d_out, int out_size, void* d_ws, size_t ws_size,
                              hipStream_t stream) {
    const float* memory  = (const float*)d_in[0];  // [C,N,D]
    const float* confid  = (const float*)d_in[1];  // [C,N]
    const float* feats   = (const float*)d_in[2];  // [B,D]
    const float* targets = (const float*)d_in[3];  // [B,C]
    const int*   bconf   = (const int*)d_in[4];    // [B]
    const int*   mask    = (const int*)d_in[5];    // [B]
    float* out = (float*)d_out;

    int* cls = (int*)d_ws;            // [B]
    int* src = cls + B_SAMPLES;       // [C*N]

    argmax_kernel<<<(B_SAMPLES + 3) / 4, 256, 0, stream>>>(targets, mask, cls);
    simulate_kernel<<<C_CLASSES, 64, 0, stream>>>(confid, bconf, mask, cls, src);
    writeback_kernel<<<(C_CLASSES * N_SLOTS) / 4, 256, 0, stream>>>(memory, feats, src, out);
}